// Round 2
// baseline (5320.570 us; speedup 1.0000x reference)
//
#include <hip/hip_runtime.h>
#include <hip/hip_bf16.h>
#include <math.h>

#define H 1024
#define V 32000
#define B 64
#define S 64
#define T 13

typedef __bf16 bf16x8 __attribute__((ext_vector_type(8)));
typedef float f32x4 __attribute__((ext_vector_type(4)));

__device__ __forceinline__ float sigmoidf_fast(float x) { return 1.0f / (1.0f + __expf(-x)); }
// tanh via exp2-based __expf; saturates correctly at +/-1 for |x| large.
__device__ __forceinline__ float tanhf_fast(float x) { return 1.0f - 2.0f / (1.0f + __expf(2.0f * x)); }

// C[m, n] = bias[n] + sum_k A[m, k] * W[n, k], f32 in/out, bf16 MFMA inside.
// Block = 256 threads (4 waves). Block tile: 64 (M) x 64*NT (N).
// grid.x = N/(64*NT), grid.y = M/64. Wave w covers n-slice [n_base, n_base+16*NT).
// Fragment layout (m89-verified): A/B operand idx=lane&15, k=(lane>>4)*8+j;
// C/D col=lane&15, row=(lane>>4)*4+reg.
template<int NT>
__global__ __launch_bounds__(256) void gemm_mfma(
    const float* __restrict__ A, int lda,
    const float* __restrict__ W, int ldw,
    const float* __restrict__ bias,
    float* __restrict__ C, int ldc, int K)
{
    const int tid = threadIdx.x;
    const int lane = tid & 63, wv = tid >> 6;
    const int row = lane & 15;
    const int kq = (lane >> 4) * 8;
    const int m_base = blockIdx.y * 64;
    const int n_base = blockIdx.x * (64 * NT) + wv * (16 * NT);

    const float* Ap = A + (size_t)(m_base + row) * lda + kq;
    const float* Wp = W + (size_t)(n_base + row) * ldw + kq;

    f32x4 acc[4][NT];
#pragma unroll
    for (int i = 0; i < 4; ++i)
#pragma unroll
        for (int j = 0; j < NT; ++j) acc[i][j] = (f32x4){0.f, 0.f, 0.f, 0.f};

    for (int k0 = 0; k0 < K; k0 += 32) {
        bf16x8 af[4], bfr[NT];
#pragma unroll
        for (int i = 0; i < 4; ++i) {
            const float* p = Ap + (size_t)i * 16 * lda + k0;
            float4 lo = *(const float4*)p;
            float4 hi = *(const float4*)(p + 4);
            bf16x8 v;
            v[0] = (__bf16)lo.x; v[1] = (__bf16)lo.y; v[2] = (__bf16)lo.z; v[3] = (__bf16)lo.w;
            v[4] = (__bf16)hi.x; v[5] = (__bf16)hi.y; v[6] = (__bf16)hi.z; v[7] = (__bf16)hi.w;
            af[i] = v;
        }
#pragma unroll
        for (int j = 0; j < NT; ++j) {
            const float* p = Wp + (size_t)j * 16 * ldw + k0;
            float4 lo = *(const float4*)p;
            float4 hi = *(const float4*)(p + 4);
            bf16x8 v;
            v[0] = (__bf16)lo.x; v[1] = (__bf16)lo.y; v[2] = (__bf16)lo.z; v[3] = (__bf16)lo.w;
            v[4] = (__bf16)hi.x; v[5] = (__bf16)hi.y; v[6] = (__bf16)hi.z; v[7] = (__bf16)hi.w;
            bfr[j] = v;
        }
#pragma unroll
        for (int i = 0; i < 4; ++i)
#pragma unroll
            for (int j = 0; j < NT; ++j)
                acc[i][j] = __builtin_amdgcn_mfma_f32_16x16x32_bf16(af[i], bfr[j], acc[i][j], 0, 0, 0);
    }

    const int cm = (lane >> 4) * 4;
#pragma unroll
    for (int j = 0; j < NT; ++j) {
        const int n = n_base + 16 * j + row;
        const float bv = bias ? bias[n] : 0.f;
#pragma unroll
        for (int i = 0; i < 4; ++i) {
            float* Cp = C + (size_t)(m_base + 16 * i + cm) * ldc + n;
#pragma unroll
            for (int r = 0; r < 4; ++r) Cp[(size_t)r * ldc] = acc[i][j][r] + bv;
        }
    }
}

// Per step: gather embedding row into xi[:, :H] (f32).
__global__ void embed_gather(const int* __restrict__ target, const float* __restrict__ emb,
                             float* __restrict__ xi, int t) {
    const int b = blockIdx.x, tid = threadIdx.x;
    const int tok = (t == 0) ? 2 : target[b * T + t - 1];
    ((float4*)(xi + (size_t)b * 2 * H))[tid] = ((const float4*)(emb + (size_t)tok * H))[tid];
}

// One block per batch row: scores = Va . tanh(q + keys_proj), softmax over S, ctx = w @ enc_out.
// bv (scalar score bias) cancels in softmax; omitted.
__global__ void attn_ctx(const float* __restrict__ q, const float* __restrict__ keys_proj,
                         const float* __restrict__ enc_out, const float* __restrict__ Va,
                         float* __restrict__ xi, float* __restrict__ attn_out, int t) {
    const int b = blockIdx.x, tid = threadIdx.x;
    __shared__ float qs[H];
    __shared__ float vas[H];
    __shared__ float sw[S];
    const float* qb = q + (size_t)b * H;
    for (int i = tid; i < H; i += 256) { qs[i] = qb[i]; vas[i] = Va[i]; }
    __syncthreads();
    const int s = tid >> 2, hq = tid & 3;
    const float* kp = keys_proj + ((size_t)b * S + s) * H;
    float part = 0.f;
    for (int j = 0; j < H / 4; ++j) {
        int hh = j * 4 + hq;
        part += vas[hh] * tanhf_fast(qs[hh] + kp[hh]);
    }
    part += __shfl_xor(part, 1);
    part += __shfl_xor(part, 2);
    if (hq == 0) sw[s] = part;
    __syncthreads();
    if (tid < 64) {
        float v = sw[tid];
        float m = v;
#pragma unroll
        for (int o = 32; o; o >>= 1) m = fmaxf(m, __shfl_xor(m, o));
        float e = __expf(v - m);
        float ssum = e;
#pragma unroll
        for (int o = 32; o; o >>= 1) ssum += __shfl_xor(ssum, o);
        float w = e / ssum;
        sw[tid] = w;
        attn_out[((size_t)b * T + t) * S + tid] = w;
    }
    __syncthreads();
    const float* Eb = enc_out + (size_t)b * S * H;
    float a0 = 0.f, a1 = 0.f, a2 = 0.f, a3 = 0.f;
    for (int s2 = 0; s2 < S; ++s2) {
        float w = sw[s2];
        const float* row = Eb + (size_t)s2 * H;
        a0 += w * row[tid];
        a1 += w * row[tid + 256];
        a2 += w * row[tid + 512];
        a3 += w * row[tid + 768];
    }
    float* ctx = xi + (size_t)b * 2 * H + H;
    ctx[tid] = a0; ctx[tid + 256] = a1; ctx[tid + 512] = a2; ctx[tid + 768] = a3;
}

// One block per batch row: LSTM cell (torch i,f,g,o order; gates = g1 + g2) + LayerNorm into nh.
__global__ void cell_ln(const float* __restrict__ g1, const float* __restrict__ g2,
                        float* __restrict__ h, float* __restrict__ c, float* __restrict__ nh,
                        const float* __restrict__ ln_g, const float* __restrict__ ln_b) {
    const int b = blockIdx.x, tid = threadIdx.x;
    const float* g1b = g1 + (size_t)b * 4 * H;
    const float* g2b = g2 + (size_t)b * 4 * H;
    float* cb = c + (size_t)b * H;
    float* hb = h + (size_t)b * H;
    float hv[4];
    float sum = 0.f, sumsq = 0.f;
#pragma unroll
    for (int j = 0; j < 4; ++j) {
        int n = tid + j * 256;
        float ig = sigmoidf_fast(g1b[n] + g2b[n]);
        float fg = sigmoidf_fast(g1b[n + H] + g2b[n + H]);
        float gg = tanhf_fast(g1b[n + 2 * H] + g2b[n + 2 * H]);
        float og = sigmoidf_fast(g1b[n + 3 * H] + g2b[n + 3 * H]);
        float cv = fg * cb[n] + ig * gg;
        cb[n] = cv;
        float hn = og * tanhf_fast(cv);
        hb[n] = hn;
        hv[j] = hn;
        sum += hn;
        sumsq += hn * hn;
    }
#pragma unroll
    for (int o = 32; o; o >>= 1) { sum += __shfl_xor(sum, o); sumsq += __shfl_xor(sumsq, o); }
    __shared__ float rs[4], rq[4];
    if ((tid & 63) == 0) { rs[tid >> 6] = sum; rq[tid >> 6] = sumsq; }
    __syncthreads();
    sum = rs[0] + rs[1] + rs[2] + rs[3];
    sumsq = rq[0] + rq[1] + rq[2] + rq[3];
    float mu = sum * (1.f / H);
    float var = sumsq * (1.f / H) - mu * mu;
    float inv = rsqrtf(var + 1e-5f);
#pragma unroll
    for (int j = 0; j < 4; ++j) {
        int n = tid + j * 256;
        nh[(size_t)b * H + n] = (hv[j] - mu) * inv * ln_g[n] + ln_b[n];
    }
}

// In-place log-softmax over V for row (b, t) of logp. 1024 threads.
__global__ void logsoftmax_inplace(float* __restrict__ out, int t) {
    const int b = blockIdx.x, tid = threadIdx.x;
    float* row = out + ((size_t)b * T + t) * V;
    float m = -3.4e38f;
    for (int v = tid; v < V; v += 1024) m = fmaxf(m, row[v]);
#pragma unroll
    for (int o = 32; o; o >>= 1) m = fmaxf(m, __shfl_xor(m, o));
    __shared__ float red[16];
    if ((tid & 63) == 0) red[tid >> 6] = m;
    __syncthreads();
    if (tid < 16) {
        float mm = red[tid];
#pragma unroll
        for (int o = 8; o; o >>= 1) mm = fmaxf(mm, __shfl_xor(mm, o));
        red[tid] = mm;
    }
    __syncthreads();
    m = red[0];
    float ssum = 0.f;
    for (int v = tid; v < V; v += 1024) ssum += __expf(row[v] - m);
#pragma unroll
    for (int o = 32; o; o >>= 1) ssum += __shfl_xor(ssum, o);
    __shared__ float red2[16];
    if ((tid & 63) == 0) red2[tid >> 6] = ssum;
    __syncthreads();
    if (tid < 16) {
        float s2 = red2[tid];
#pragma unroll
        for (int o = 8; o; o >>= 1) s2 += __shfl_xor(s2, o);
        red2[tid] = s2;
    }
    __syncthreads();
    float L = m + logf(red2[0]);
    for (int v = tid; v < V; v += 1024) row[v] -= L;
}

// Copy two 64x1024 f32 buffers (h/c init and final h/c output).
__global__ void copy2(const float* __restrict__ a, const float* __restrict__ bsrc,
                      float* __restrict__ x, float* __restrict__ y) {
    size_t i = (size_t)blockIdx.x * 256 + threadIdx.x;
    ((float4*)x)[i] = ((const float4*)a)[i];
    ((float4*)y)[i] = ((const float4*)bsrc)[i];
}

extern "C" void kernel_launch(void* const* d_in, const int* in_sizes, int n_in,
                              void* d_out, int out_size, void* d_ws, size_t ws_size,
                              hipStream_t stream) {
    const float* enc_out = (const float*)d_in[0];
    const float* enc_h   = (const float*)d_in[1];
    const float* enc_c   = (const float*)d_in[2];
    const int*   target  = (const int*)d_in[3];
    const float* emb     = (const float*)d_in[4];
    const float* Wa      = (const float*)d_in[5];
    const float* ba      = (const float*)d_in[6];
    const float* Ua      = (const float*)d_in[7];
    const float* bu      = (const float*)d_in[8];
    const float* Va      = (const float*)d_in[9];
    // d_in[10] = bv: constant score offset, cancels in softmax; omitted.
    const float* W_ih    = (const float*)d_in[11];
    const float* W_hh    = (const float*)d_in[12];
    const float* b_ih    = (const float*)d_in[13];
    const float* b_hh    = (const float*)d_in[14];
    const float* ln_g    = (const float*)d_in[15];
    const float* ln_b    = (const float*)d_in[16];
    const float* outW    = (const float*)d_in[17];
    const float* outb    = (const float*)d_in[18];
    float* out = (float*)d_out;

    float* ws    = (float*)d_ws;
    float* keys  = ws;                          // B*S*H
    float* h     = keys + (size_t)B * S * H;    // B*H
    float* c     = h + (size_t)B * H;           // B*H
    float* q     = c + (size_t)B * H;           // B*H
    float* xi    = q + (size_t)B * H;           // B*2H  (x | ctx)
    float* g1    = xi + (size_t)B * 2 * H;      // B*4H
    float* g2    = g1 + (size_t)B * 4 * H;      // B*4H
    float* nh    = g2 + (size_t)B * 4 * H;      // B*H

    const size_t HOFF = (size_t)B * T * V;
    const size_t COFF = HOFF + (size_t)B * H;
    const size_t AOFF = COFF + (size_t)B * H;

    // keys_proj = enc_out @ Ua^T + bu   [B*S, H]
    hipLaunchKernelGGL((gemm_mfma<2>), dim3(H / 128, (B * S) / 64), dim3(256), 0, stream,
                       enc_out, H, Ua, H, bu, keys, H, H);
    hipLaunchKernelGGL(copy2, dim3(64), dim3(256), 0, stream, enc_h, enc_c, h, c);

    for (int t = 0; t < T; ++t) {
        hipLaunchKernelGGL(embed_gather, dim3(B), dim3(256), 0, stream, target, emb, xi, t);
        // q = h @ Wa^T + ba
        hipLaunchKernelGGL((gemm_mfma<1>), dim3(H / 64, 1), dim3(256), 0, stream,
                           h, H, Wa, H, ba, q, H, H);
        hipLaunchKernelGGL(attn_ctx, dim3(B), dim3(256), 0, stream,
                           q, keys, enc_out, Va, xi, out + AOFF, t);
        // g1 = xi @ W_ih^T + b_ih ; g2 = h @ W_hh^T + b_hh
        hipLaunchKernelGGL((gemm_mfma<1>), dim3(4 * H / 64, 1), dim3(256), 0, stream,
                           xi, 2 * H, W_ih, 2 * H, b_ih, g1, 4 * H, 2 * H);
        hipLaunchKernelGGL((gemm_mfma<1>), dim3(4 * H / 64, 1), dim3(256), 0, stream,
                           h, H, W_hh, H, b_hh, g2, 4 * H, H);
        hipLaunchKernelGGL(cell_ln, dim3(B), dim3(256), 0, stream,
                           g1, g2, h, c, nh, ln_g, ln_b);
        // logits straight into logp slot (row stride T*V), then in-place log-softmax
        hipLaunchKernelGGL((gemm_mfma<2>), dim3(V / 128, 1), dim3(256), 0, stream,
                           nh, H, outW, H, outb, out + (size_t)t * V, T * V, H);
        hipLaunchKernelGGL(logsoftmax_inplace, dim3(B), dim3(1024), 0, stream, out, t);
    }
    hipLaunchKernelGGL(copy2, dim3(64), dim3(256), 0, stream, h, c, out + HOFF, out + COFF);
}